// Round 8
// baseline (67.911 us; speedup 1.0000x reference)
//
#include <hip/hip_runtime.h>

#define NPIX (384*384)        // 147456
#define NSAMP 32
#define ROWS 64               // 32 region rows + 32 affinity rows
#define BINS 1024             // exponent(8) + 3 mantissa bits; l in [0,1) -> bin <= 1015
#define REPL 2                // LDS histogram replication
#define THREADS 256
#define BLKROW 36
#define EPB (NPIX / BLKROW)   // 4096 elements per block
#define NIT (EPB / (THREADS * 4))   // 4 float4-iterations per thread
#define FXSCALE 268435456.0f  // 2^28 fixed-point scale for packed bin sums
#define FXINV   3.7252902984619141e-9
#define MASK46  ((1ULL << 46) - 1)
// packed bin: (count << 46) | fixed_point_sum.
// per block: count <= 4096 < 2^18 headroom; sum < 4096 * 2^28 = 2^40 < 2^46.

// workspace: part[ROWS][BLKROW][BINS] u64 partial histograms (18.9 MB, plain
// stores, never needs zeroing), then stats (per row: 0=n_pos 1=pos_sum).
#define PART_BYTES ((size_t)ROWS * BLKROW * BINS * 8)
#define STATS_OFF  PART_BYTES

__global__ __launch_bounds__(THREADS) void k_zero(unsigned int* __restrict__ stats,
                                                  float* __restrict__ out)
{
    int i = threadIdx.x;           // single block
    if (i < ROWS * 4) stats[i] = 0u;
    if (i == 0) out[0] = 0.f;
}

// Per (row, chunk) block: loss for 4096 pixels -> 1024-bin packed (cnt,sum)
// histogram in LDS (2-way replicated u64), flushed with plain coalesced
// stores to a private partial slot. (R4's proven-fastest inner config.)
__global__ __launch_bounds__(THREADS) void k_hist(
    const float* __restrict__ gt_r, const float* __restrict__ gt_a,
    const float* __restrict__ pr_r, const float* __restrict__ pr_a,
    const float* __restrict__ conf,
    unsigned long long* __restrict__ part,
    unsigned int* __restrict__ stats_u, float* __restrict__ stats_f)
{
    __shared__ unsigned long long s_hist[BINS * REPL];   // 16 KB
    const int tid = threadIdx.x;
    const int row = blockIdx.y;
    const int chunk = blockIdx.x;
    const int samp = row & (NSAMP - 1);
    const float* gt = (row < NSAMP) ? gt_r : gt_a;
    const float* pr = (row < NSAMP) ? pr_r : pr_a;
    const unsigned copy = tid & (REPL - 1);

    for (int i = tid; i < BINS * REPL; i += THREADS) s_hist[i] = 0ULL;
    __syncthreads();

    size_t base = (size_t)samp * NPIX + (size_t)chunk * EPB + (size_t)tid * 4;
    unsigned pc = 0; float ps = 0.f;
    #pragma unroll
    for (int it = 0; it < NIT; ++it) {
        size_t idx = base + (size_t)it * THREADS * 4;
        float4 g = *(const float4*)(gt + idx);
        float4 p = *(const float4*)(pr + idx);
        float4 c = *(const float4*)(conf + idx);
        float gv[4] = {g.x, g.y, g.z, g.w};
        float pv[4] = {p.x, p.y, p.z, p.w};
        float cv[4] = {c.x, c.y, c.z, c.w};
        #pragma unroll
        for (int j = 0; j < 4; ++j) {
            float d = pv[j] - gv[j];
            float l = d * d * cv[j];
            if (gv[j] >= 0.1f) { pc++; ps += l; }
            else {
                unsigned bin = __float_as_uint(l) >> 20;   // l < 1 -> bin <= 1015
                unsigned long long pk =
                    (1ULL << 46) | (unsigned long long)(unsigned)(l * FXSCALE);
                atomicAdd(&s_hist[(bin << 1) | copy], pk);
            }
        }
    }

    // wave-reduce positive stats, one global atomic per wave (tiny traffic)
    for (int off = 32; off; off >>= 1) {
        pc += __shfl_down(pc, off);
        ps += __shfl_down(ps, off);
    }
    if ((tid & 63) == 0 && pc) {
        atomicAdd(&stats_u[row * 4 + 0], pc);
        atomicAdd(&stats_f[row * 4 + 1], ps);
    }
    __syncthreads();

    // private flush: plain coalesced stores, zero contention, no zero-init
    unsigned long long* dst = part + ((size_t)row * BLKROW + chunk) * BINS;
    for (int i = tid; i < BINS; i += THREADS)
        dst[i] = s_hist[i << 1] + s_hist[(i << 1) | 1];
}

// Per row: sum 36 partial packed histograms, parallel descending suffix-scan
// over (count, exact-sum); boundary bin's partial take approximated by the
// bin's true mean (error ~ kpp/k * binwidth -> ~1e-3 on the output).
__global__ __launch_bounds__(THREADS) void k_sel(
    const unsigned long long* __restrict__ part,
    const unsigned int* __restrict__ stats_u, const float* __restrict__ stats_f,
    float* __restrict__ out)
{
    const int row = blockIdx.x;           // 0..63
    const int tid = threadIdx.x;

    unsigned n_pos = stats_u[row * 4 + 0];
    float pos_sum  = stats_f[row * 4 + 1];
    unsigned n_neg = NPIX - n_pos;
    float pos_part = (n_pos > 0u) ? pos_sum / (float)n_pos : 0.f;
    if (n_neg == 0u) {
        if (tid == 0) atomicAdd(out, (pos_part - 1.f) / (float)NSAMP); // sentinel -1
        return;
    }
    unsigned k;
    if (n_pos > 0u) {
        k = 3u * n_pos;
        if (k > n_neg) k = n_neg;
        if (k < 1u) k = 1u;
    } else {
        k = 500u;   // fallback: top-500 (all pixels are negatives when n_pos==0)
    }

    // accumulate my 4 descending-rank bins over the 36 chunk partials.
    // rank r = tid*4+j -> bin = 1023 - r; thread's bins are the contiguous
    // ascending range [1020-4*tid, 1023-4*tid].
    const unsigned long long* base = part + (size_t)row * BLKROW * BINS;
    unsigned long long acc[4] = {0ULL, 0ULL, 0ULL, 0ULL};
    for (int ch = 0; ch < BLKROW; ++ch) {
        const unsigned long long* q = base + (size_t)ch * BINS + (BINS - 4 - tid * 4);
        acc[0] += q[3]; acc[1] += q[2]; acc[2] += q[1]; acc[3] += q[0];
    }
    unsigned c[4]; float s[4];
    unsigned tc = 0; float ts = 0.f;
    #pragma unroll
    for (int j = 0; j < 4; ++j) {
        c[j] = (unsigned)(acc[j] >> 46);
        s[j] = (float)((double)(acc[j] & MASK46) * FXINV);
        tc += c[j]; ts += s[j];
    }

    unsigned lane = tid & 63, w = tid >> 6;
    unsigned ic = tc; float is = ts;
    #pragma unroll
    for (int off = 1; off < 64; off <<= 1) {
        unsigned uc = __shfl_up(ic, off);
        float    us = __shfl_up(is, off);
        if (lane >= off) { ic += uc; is += us; }
    }
    __shared__ unsigned wtc[4]; __shared__ float wts[4];
    if (lane == 63) { wtc[w] = ic; wts[w] = is; }
    __syncthreads();
    unsigned woc = 0; float wos = 0.f;
    for (unsigned i = 0; i < w; ++i) { woc += wtc[i]; wos += wts[i]; }
    unsigned before_c = woc + ic - tc;   // count strictly above my first rank
    float    before_s = wos + is - ts;

    #pragma unroll
    for (int j = 0; j < 4; ++j) {
        if (before_c < k && before_c + c[j] >= k) {
            unsigned kpp = k - before_c;             // 1 <= kpp <= c[j]
            float mean = s[j] / (float)c[j];
            float topk = before_s + (float)kpp * mean;
            atomicAdd(out, (pos_part + topk / (float)k) / (float)NSAMP);
        }
        before_c += c[j]; before_s += s[j];
    }
}

extern "C" void kernel_launch(void* const* d_in, const int* in_sizes, int n_in,
                              void* d_out, int out_size, void* d_ws, size_t ws_size,
                              hipStream_t stream)
{
    (void)in_sizes; (void)n_in; (void)out_size; (void)ws_size;
    const float* gt_r = (const float*)d_in[0];
    const float* gt_a = (const float*)d_in[1];
    const float* pr_r = (const float*)d_in[2];
    const float* pr_a = (const float*)d_in[3];
    const float* conf = (const float*)d_in[4];

    char* ws = (char*)d_ws;
    unsigned long long* part = (unsigned long long*)ws;
    unsigned int* stats_u = (unsigned int*)(ws + STATS_OFF);
    float*        stats_f = (float*)       (ws + STATS_OFF);

    k_zero<<<1, THREADS, 0, stream>>>(stats_u, (float*)d_out);

    dim3 gridH(BLKROW, ROWS);
    k_hist<<<gridH, THREADS, 0, stream>>>(gt_r, gt_a, pr_r, pr_a, conf,
                                          part, stats_u, stats_f);
    k_sel<<<ROWS, THREADS, 0, stream>>>(part, stats_u, stats_f, (float*)d_out);
}

// Round 9
// 39.543 us; speedup vs baseline: 1.7174x; 1.7174x over previous
//
#include <hip/hip_runtime.h>

#define NPIX (384*384)        // 147456
#define NSAMP 32
#define ROWS 64               // 32 region rows + 32 affinity rows
#define BINS 1024             // exponent(8) + 3 mantissa bits; l in [0,1) -> bin <= 1015
#define REPL 2                // LDS histogram replication
#define THREADS 256
#define BLKROW 36
#define EPB (NPIX / BLKROW)   // 4096 elements per block
#define NIT (EPB / (THREADS * 4))   // 4 float4-iterations per thread
#define FXSCALE 268435456.0f  // 2^28 fixed-point scale for packed bin sums
#define FXINV   3.7252902984619141e-9
#define MASK46  ((1ULL << 46) - 1)
// packed bin: (count << 46) | fixed_point_sum.
// per block: count <= 4096; sum < 4096 * 2^28 = 2^40 < 2^46.

// workspace: part[ROWS][BLKROW][BINS] u64 partial histograms (18.9 MB, plain
// stores, never needs zeroing), then stats (per row: 0=n_pos 1=pos_sum).
#define PART_BYTES ((size_t)ROWS * BLKROW * BINS * 8)
#define STATS_OFF  PART_BYTES

__global__ __launch_bounds__(THREADS) void k_zero(unsigned int* __restrict__ stats,
                                                  float* __restrict__ out)
{
    int i = threadIdx.x;           // single block
    if (i < ROWS * 4) stats[i] = 0u;
    if (i == 0) out[0] = 0.f;
}

// Per (row, chunk) block: loss for 4096 pixels -> 1024-bin packed (cnt,sum)
// histogram in LDS (2-way replicated u64), flushed with plain coalesced
// stores to a private partial slot. Stats buffered in LDS: exactly ONE
// global atomic pair per block (R3/R4's proven path — 9216 per-wave global
// stats atomics was the R6-R8 regression suspect).
__global__ __launch_bounds__(THREADS) void k_hist(
    const float* __restrict__ gt_r, const float* __restrict__ gt_a,
    const float* __restrict__ pr_r, const float* __restrict__ pr_a,
    const float* __restrict__ conf,
    unsigned long long* __restrict__ part,
    unsigned int* __restrict__ stats_u, float* __restrict__ stats_f)
{
    __shared__ unsigned long long s_hist[BINS * REPL];   // 16 KB
    __shared__ unsigned int s_pc;
    __shared__ float s_ps;
    const int tid = threadIdx.x;
    const int row = blockIdx.y;
    const int chunk = blockIdx.x;
    const int samp = row & (NSAMP - 1);
    const float* gt = (row < NSAMP) ? gt_r : gt_a;
    const float* pr = (row < NSAMP) ? pr_r : pr_a;
    const unsigned copy = tid & (REPL - 1);

    for (int i = tid; i < BINS * REPL; i += THREADS) s_hist[i] = 0ULL;
    if (tid == 0) { s_pc = 0u; s_ps = 0.f; }
    __syncthreads();

    size_t base = (size_t)samp * NPIX + (size_t)chunk * EPB + (size_t)tid * 4;
    unsigned pc = 0; float ps = 0.f;
    #pragma unroll
    for (int it = 0; it < NIT; ++it) {
        size_t idx = base + (size_t)it * THREADS * 4;
        float4 g = *(const float4*)(gt + idx);
        float4 p = *(const float4*)(pr + idx);
        float4 c = *(const float4*)(conf + idx);
        float gv[4] = {g.x, g.y, g.z, g.w};
        float pv[4] = {p.x, p.y, p.z, p.w};
        float cv[4] = {c.x, c.y, c.z, c.w};
        #pragma unroll
        for (int j = 0; j < 4; ++j) {
            float d = pv[j] - gv[j];
            float l = d * d * cv[j];
            if (gv[j] >= 0.1f) { pc++; ps += l; }
            else {
                unsigned bin = __float_as_uint(l) >> 20;   // l < 1 -> bin <= 1015
                unsigned long long pk =
                    (1ULL << 46) | (unsigned long long)(unsigned)(l * FXSCALE);
                atomicAdd(&s_hist[(bin << 1) | copy], pk);
            }
        }
    }

    // wave-reduce positive stats -> LDS atomic per wave (NO global traffic here)
    for (int off = 32; off; off >>= 1) {
        pc += __shfl_down(pc, off);
        ps += __shfl_down(ps, off);
    }
    if ((tid & 63) == 0) { atomicAdd(&s_pc, pc); atomicAdd(&s_ps, ps); }
    __syncthreads();

    // private flush: plain coalesced stores, zero contention, no zero-init
    unsigned long long* dst = part + ((size_t)row * BLKROW + chunk) * BINS;
    for (int i = tid; i < BINS; i += THREADS)
        dst[i] = s_hist[i << 1] + s_hist[(i << 1) | 1];

    // single global stats atomic pair per block
    if (tid == 0 && s_pc) {
        atomicAdd(&stats_u[row * 4 + 0], s_pc);
        atomicAdd(&stats_f[row * 4 + 1], s_ps);
    }
}

// Per row: sum 36 partial packed histograms, parallel descending suffix-scan
// over (count, exact-sum); boundary bin's partial take approximated by the
// bin's true mean (error ~ kpp/k * binwidth -> ~1e-3 on the output).
__global__ __launch_bounds__(THREADS) void k_sel(
    const unsigned long long* __restrict__ part,
    const unsigned int* __restrict__ stats_u, const float* __restrict__ stats_f,
    float* __restrict__ out)
{
    const int row = blockIdx.x;           // 0..63
    const int tid = threadIdx.x;

    unsigned n_pos = stats_u[row * 4 + 0];
    float pos_sum  = stats_f[row * 4 + 1];
    unsigned n_neg = NPIX - n_pos;
    float pos_part = (n_pos > 0u) ? pos_sum / (float)n_pos : 0.f;
    if (n_neg == 0u) {
        if (tid == 0) atomicAdd(out, (pos_part - 1.f) / (float)NSAMP); // sentinel -1
        return;
    }
    unsigned k;
    if (n_pos > 0u) {
        k = 3u * n_pos;
        if (k > n_neg) k = n_neg;
        if (k < 1u) k = 1u;
    } else {
        k = 500u;   // fallback: top-500 (all pixels are negatives when n_pos==0)
    }

    // accumulate my 4 descending-rank bins over the 36 chunk partials.
    const unsigned long long* base = part + (size_t)row * BLKROW * BINS;
    unsigned long long acc[4] = {0ULL, 0ULL, 0ULL, 0ULL};
    for (int ch = 0; ch < BLKROW; ++ch) {
        const unsigned long long* q = base + (size_t)ch * BINS + (BINS - 4 - tid * 4);
        acc[0] += q[3]; acc[1] += q[2]; acc[2] += q[1]; acc[3] += q[0];
    }
    unsigned c[4]; float s[4];
    unsigned tc = 0; float ts = 0.f;
    #pragma unroll
    for (int j = 0; j < 4; ++j) {
        c[j] = (unsigned)(acc[j] >> 46);
        s[j] = (float)((double)(acc[j] & MASK46) * FXINV);
        tc += c[j]; ts += s[j];
    }

    unsigned lane = tid & 63, w = tid >> 6;
    unsigned ic = tc; float is = ts;
    #pragma unroll
    for (int off = 1; off < 64; off <<= 1) {
        unsigned uc = __shfl_up(ic, off);
        float    us = __shfl_up(is, off);
        if (lane >= off) { ic += uc; is += us; }
    }
    __shared__ unsigned wtc[4]; __shared__ float wts[4];
    if (lane == 63) { wtc[w] = ic; wts[w] = is; }
    __syncthreads();
    unsigned woc = 0; float wos = 0.f;
    for (unsigned i = 0; i < w; ++i) { woc += wtc[i]; wos += wts[i]; }
    unsigned before_c = woc + ic - tc;   // count strictly above my first rank
    float    before_s = wos + is - ts;

    #pragma unroll
    for (int j = 0; j < 4; ++j) {
        if (before_c < k && before_c + c[j] >= k) {
            unsigned kpp = k - before_c;             // 1 <= kpp <= c[j]
            float mean = s[j] / (float)c[j];
            float topk = before_s + (float)kpp * mean;
            atomicAdd(out, (pos_part + topk / (float)k) / (float)NSAMP);
        }
        before_c += c[j]; before_s += s[j];
    }
}

extern "C" void kernel_launch(void* const* d_in, const int* in_sizes, int n_in,
                              void* d_out, int out_size, void* d_ws, size_t ws_size,
                              hipStream_t stream)
{
    (void)in_sizes; (void)n_in; (void)out_size; (void)ws_size;
    const float* gt_r = (const float*)d_in[0];
    const float* gt_a = (const float*)d_in[1];
    const float* pr_r = (const float*)d_in[2];
    const float* pr_a = (const float*)d_in[3];
    const float* conf = (const float*)d_in[4];

    char* ws = (char*)d_ws;
    unsigned long long* part = (unsigned long long*)ws;
    unsigned int* stats_u = (unsigned int*)(ws + STATS_OFF);
    float*        stats_f = (float*)       (ws + STATS_OFF);

    k_zero<<<1, THREADS, 0, stream>>>(stats_u, (float*)d_out);

    dim3 gridH(BLKROW, ROWS);
    k_hist<<<gridH, THREADS, 0, stream>>>(gt_r, gt_a, pr_r, pr_a, conf,
                                          part, stats_u, stats_f);
    k_sel<<<ROWS, THREADS, 0, stream>>>(part, stats_u, stats_f, (float*)d_out);
}

// Round 10
// 30.567 us; speedup vs baseline: 2.2217x; 1.2936x over previous
//
#include <hip/hip_runtime.h>

#define NPIX (384*384)        // 147456
#define NSAMP 32
#define ROWS 64               // 32 region rows + 32 affinity rows
#define BINS 1024             // exponent(8) + 3 mantissa bits; l in [0,1) -> bin <= 1015
#define REPL 2                // LDS histogram replication
#define THREADS 256
#define BLKROW 36
#define EPB (NPIX / BLKROW)   // 4096 elements per block
#define NIT (EPB / (THREADS * 4))   // 4 float4-iterations per thread
#define FXSCALE 268435456.0f  // 2^28 fixed-point scale for packed bin sums
#define FXINV   3.7252902984619141e-9
#define MASK46  ((1ULL << 46) - 1)
// packed bin: (count << 46) | fixed_point_sum.
// per block: count <= 4096; sum < 4096 * 2^28 = 2^40 < 2^46.
// row totals:  count <= 147456 < 2^17.2 (fits 46..63); sum < 36*2^40 < 2^46.

// workspace layout (no zero-init needed anywhere):
//   part [ROWS][BLKROW][BINS] u64   partial histograms (18.9 MB, plain stores)
//   pstat[ROWS][BLKROW]       u64   per-block (n_pos<<32 | f32bits(pos_sum))
#define PART_U64   ((size_t)ROWS * BLKROW * BINS)
#define PSTAT_OFF  (PART_U64 * 8)

// Per (row, chunk) block: loss for 4096 pixels -> 1024-bin packed (cnt,sum)
// histogram in LDS (2-way replicated u64), flushed with plain coalesced
// stores to a private partial slot. Positive stats also go to a private
// slot: this kernel issues ZERO global atomics (R9 lesson: contended
// device-scope atomics cost ~17us while invisible in SQ counters).
__global__ __launch_bounds__(THREADS) void k_hist(
    const float* __restrict__ gt_r, const float* __restrict__ gt_a,
    const float* __restrict__ pr_r, const float* __restrict__ pr_a,
    const float* __restrict__ conf,
    unsigned long long* __restrict__ part,
    unsigned long long* __restrict__ pstat,
    float* __restrict__ out)
{
    __shared__ unsigned long long s_hist[BINS * REPL];   // 16 KB
    __shared__ unsigned int s_pc;
    __shared__ float s_ps;
    const int tid = threadIdx.x;
    const int row = blockIdx.y;
    const int chunk = blockIdx.x;
    const int samp = row & (NSAMP - 1);
    const float* gt = (row < NSAMP) ? gt_r : gt_a;
    const float* pr = (row < NSAMP) ? pr_r : pr_a;
    const unsigned copy = tid & (REPL - 1);

    // zero d_out for k_sel's atomicAdd (safe: consumed only after this kernel)
    if (row == 0 && chunk == 0 && tid == 0) out[0] = 0.f;

    for (int i = tid; i < BINS * REPL; i += THREADS) s_hist[i] = 0ULL;
    if (tid == 0) { s_pc = 0u; s_ps = 0.f; }
    __syncthreads();

    // issue all 12 vector loads up front for memory-level parallelism
    size_t base = (size_t)samp * NPIX + (size_t)chunk * EPB + (size_t)tid * 4;
    float4 g[NIT], p[NIT], c[NIT];
    #pragma unroll
    for (int it = 0; it < NIT; ++it) {
        size_t idx = base + (size_t)it * THREADS * 4;
        g[it] = *(const float4*)(gt + idx);
        p[it] = *(const float4*)(pr + idx);
        c[it] = *(const float4*)(conf + idx);
    }

    unsigned pc = 0; float ps = 0.f;
    #pragma unroll
    for (int it = 0; it < NIT; ++it) {
        float gv[4] = {g[it].x, g[it].y, g[it].z, g[it].w};
        float pv[4] = {p[it].x, p[it].y, p[it].z, p[it].w};
        float cv[4] = {c[it].x, c[it].y, c[it].z, c[it].w};
        #pragma unroll
        for (int j = 0; j < 4; ++j) {
            float d = pv[j] - gv[j];
            float l = d * d * cv[j];
            if (gv[j] >= 0.1f) { pc++; ps += l; }
            else {
                unsigned bin = __float_as_uint(l) >> 20;   // l < 1 -> bin <= 1015
                unsigned long long pk =
                    (1ULL << 46) | (unsigned long long)(unsigned)(l * FXSCALE);
                atomicAdd(&s_hist[(bin << 1) | copy], pk);
            }
        }
    }

    // wave-reduce positive stats -> LDS (no global atomics)
    for (int off = 32; off; off >>= 1) {
        pc += __shfl_down(pc, off);
        ps += __shfl_down(ps, off);
    }
    if ((tid & 63) == 0) { atomicAdd(&s_pc, pc); atomicAdd(&s_ps, ps); }
    __syncthreads();

    // private flush: plain coalesced stores, zero contention, no zero-init
    unsigned long long* dst = part + ((size_t)row * BLKROW + chunk) * BINS;
    for (int i = tid; i < BINS; i += THREADS)
        dst[i] = s_hist[i << 1] + s_hist[(i << 1) | 1];

    if (tid == 0)
        pstat[(size_t)row * BLKROW + chunk] =
            ((unsigned long long)s_pc << 32) | (unsigned long long)__float_as_uint(s_ps);
}

// Per row: reduce 36 (n_pos,pos_sum) pairs, sum 36 partial packed histograms,
// parallel descending suffix-scan over (count, exact-sum); boundary bin's
// partial take approximated by the bin's true mean (~1e-3 output error).
__global__ __launch_bounds__(THREADS) void k_sel(
    const unsigned long long* __restrict__ part,
    const unsigned long long* __restrict__ pstat,
    float* __restrict__ out)
{
    const int row = blockIdx.x;           // 0..63
    const int tid = threadIdx.x;
    __shared__ unsigned s_npos; __shared__ float s_psum;
    __shared__ unsigned wtc[4]; __shared__ float wts[4];

    // wave 0 reduces the 36 per-block stat pairs
    if (tid < 64) {
        unsigned pc = 0; float ps = 0.f;
        if (tid < BLKROW) {
            unsigned long long v = pstat[(size_t)row * BLKROW + tid];
            pc = (unsigned)(v >> 32);
            ps = __uint_as_float((unsigned)(v & 0xFFFFFFFFu));
        }
        for (int off = 32; off; off >>= 1) {
            pc += __shfl_down(pc, off);
            ps += __shfl_down(ps, off);
        }
        if (tid == 0) { s_npos = pc; s_psum = ps; }
    }

    // accumulate my 4 descending-rank bins over the 36 chunk partials.
    // rank r = tid*4+j -> bin = 1023 - r.
    const unsigned long long* base = part + (size_t)row * BLKROW * BINS;
    unsigned long long acc[4] = {0ULL, 0ULL, 0ULL, 0ULL};
    for (int ch = 0; ch < BLKROW; ++ch) {
        const unsigned long long* q = base + (size_t)ch * BINS + (BINS - 4 - tid * 4);
        acc[0] += q[3]; acc[1] += q[2]; acc[2] += q[1]; acc[3] += q[0];
    }
    __syncthreads();

    const unsigned n_pos = s_npos;
    const float pos_sum = s_psum;
    const unsigned n_neg = NPIX - n_pos;
    const float pos_part = (n_pos > 0u) ? pos_sum / (float)n_pos : 0.f;
    if (n_neg == 0u) {
        if (tid == 0) atomicAdd(out, (pos_part - 1.f) / (float)NSAMP); // sentinel -1
        return;
    }
    unsigned k;
    if (n_pos > 0u) {
        k = 3u * n_pos;
        if (k > n_neg) k = n_neg;
        if (k < 1u) k = 1u;
    } else {
        k = 500u;   // fallback: top-500 (all pixels are negatives when n_pos==0)
    }

    unsigned c[4]; float s[4];
    unsigned tc = 0; float ts = 0.f;
    #pragma unroll
    for (int j = 0; j < 4; ++j) {
        c[j] = (unsigned)(acc[j] >> 46);
        s[j] = (float)((double)(acc[j] & MASK46) * FXINV);
        tc += c[j]; ts += s[j];
    }

    unsigned lane = tid & 63, w = tid >> 6;
    unsigned ic = tc; float is = ts;
    #pragma unroll
    for (int off = 1; off < 64; off <<= 1) {
        unsigned uc = __shfl_up(ic, off);
        float    us = __shfl_up(is, off);
        if (lane >= off) { ic += uc; is += us; }
    }
    if (lane == 63) { wtc[w] = ic; wts[w] = is; }
    __syncthreads();
    unsigned woc = 0; float wos = 0.f;
    for (unsigned i = 0; i < w; ++i) { woc += wtc[i]; wos += wts[i]; }
    unsigned before_c = woc + ic - tc;   // count strictly above my first rank
    float    before_s = wos + is - ts;

    #pragma unroll
    for (int j = 0; j < 4; ++j) {
        if (before_c < k && before_c + c[j] >= k) {
            unsigned kpp = k - before_c;             // 1 <= kpp <= c[j]
            float mean = s[j] / (float)c[j];
            float topk = before_s + (float)kpp * mean;
            atomicAdd(out, (pos_part + topk / (float)k) / (float)NSAMP);
        }
        before_c += c[j]; before_s += s[j];
    }
}

extern "C" void kernel_launch(void* const* d_in, const int* in_sizes, int n_in,
                              void* d_out, int out_size, void* d_ws, size_t ws_size,
                              hipStream_t stream)
{
    (void)in_sizes; (void)n_in; (void)out_size; (void)ws_size;
    const float* gt_r = (const float*)d_in[0];
    const float* gt_a = (const float*)d_in[1];
    const float* pr_r = (const float*)d_in[2];
    const float* pr_a = (const float*)d_in[3];
    const float* conf = (const float*)d_in[4];

    char* ws = (char*)d_ws;
    unsigned long long* part  = (unsigned long long*)ws;
    unsigned long long* pstat = (unsigned long long*)(ws + PSTAT_OFF);

    dim3 gridH(BLKROW, ROWS);
    k_hist<<<gridH, THREADS, 0, stream>>>(gt_r, gt_a, pr_r, pr_a, conf,
                                          part, pstat, (float*)d_out);
    k_sel<<<ROWS, THREADS, 0, stream>>>(part, pstat, (float*)d_out);
}